// Round 1
// baseline (161.303 us; speedup 1.0000x reference)
//
#include <hip/hip_runtime.h>
#include <hip/hip_bf16.h>

// NLL of bivariate Gaussian, log-domain formulation.
// nll = z/(2(1-rho^2)) + log(2pi) + log_sx + log_sy + 0.5*log(1-rho^2)
// where log_sx = o[2], log_sy = o[3] are given directly (no exp/log round trip
// for the normalizer). Clip: -log(max(pdf, 1e-10)) == fminf(nll, -log(1e-10)).

#define THREADS 256
#define PTS_PER_THREAD 4

__device__ __forceinline__ float point_nll(float mux, float muy, float lsx,
                                           float lsy, float w, float y1, float y2) {
    const float LOG_2PI = 1.8378770664093453f;
    const float CLIP    = 23.025850929940457f; // -log(1e-10)
    float isx  = __expf(-lsx);
    float isy  = __expf(-lsy);
    float nx   = (y1 - mux) * isx;
    float ny   = (y2 - muy) * isy;
    float corr = tanhf(w);
    float omr  = fmaf(-corr, corr, 1.0f);          // 1 - rho^2
    float z    = fmaf(nx, nx, ny * ny) - 2.0f * corr * nx * ny;
    float nll  = z / (2.0f * omr) + LOG_2PI + lsx + lsy + 0.5f * __logf(omr);
    return fminf(nll, CLIP);                        // fminf(NaN,CLIP)=CLIP too
}

__global__ __launch_bounds__(THREADS) void nll_partial_kernel(
    const float* __restrict__ y, const float* __restrict__ o,
    float* __restrict__ partial, int N) {
    long long t  = (long long)blockIdx.x * THREADS + threadIdx.x;
    long long i0 = t * PTS_PER_THREAD;
    float acc = 0.0f;

    if (i0 + PTS_PER_THREAD <= (long long)N) {
        // 4 points: o_pred = 20 floats = 5 float4s; y_target = 12 floats = 3 float4s.
        const float4* o4 = (const float4*)o + t * 5;
        const float4* y4 = (const float4*)y + t * 3;
        float4 a0 = o4[0], a1 = o4[1], a2 = o4[2], a3 = o4[3], a4 = o4[4];
        float4 b0 = y4[0], b1 = y4[1], b2 = y4[2];
        float of[20] = {a0.x, a0.y, a0.z, a0.w, a1.x, a1.y, a1.z, a1.w,
                        a2.x, a2.y, a2.z, a2.w, a3.x, a3.y, a3.z, a3.w,
                        a4.x, a4.y, a4.z, a4.w};
        float yf[12] = {b0.x, b0.y, b0.z, b0.w, b1.x, b1.y, b1.z, b1.w,
                        b2.x, b2.y, b2.z, b2.w};
#pragma unroll
        for (int j = 0; j < PTS_PER_THREAD; ++j) {
            acc += point_nll(of[5 * j + 0], of[5 * j + 1], of[5 * j + 2],
                             of[5 * j + 3], of[5 * j + 4],
                             yf[3 * j + 1], yf[3 * j + 2]);
        }
    } else {
        for (long long i = i0; i < (long long)N; ++i) {
            acc += point_nll(o[i * 5 + 0], o[i * 5 + 1], o[i * 5 + 2],
                             o[i * 5 + 3], o[i * 5 + 4],
                             y[i * 3 + 1], y[i * 3 + 2]);
        }
    }

    // wave-64 reduce
#pragma unroll
    for (int off = 32; off > 0; off >>= 1) acc += __shfl_down(acc, off, 64);
    __shared__ float ws[THREADS / 64];
    if ((threadIdx.x & 63) == 0) ws[threadIdx.x >> 6] = acc;
    __syncthreads();
    if (threadIdx.x == 0) {
        float s = 0.0f;
#pragma unroll
        for (int i = 0; i < THREADS / 64; ++i) s += ws[i];
        partial[blockIdx.x] = s;
    }
}

__global__ __launch_bounds__(THREADS) void nll_final_kernel(
    const float* __restrict__ partial, int nparts, float* __restrict__ out,
    float inv_p) {
    float acc = 0.0f;
    for (int i = threadIdx.x; i < nparts; i += THREADS) acc += partial[i];
#pragma unroll
    for (int off = 32; off > 0; off >>= 1) acc += __shfl_down(acc, off, 64);
    __shared__ float ws[THREADS / 64];
    if ((threadIdx.x & 63) == 0) ws[threadIdx.x >> 6] = acc;
    __syncthreads();
    if (threadIdx.x == 0) {
        float s = 0.0f;
#pragma unroll
        for (int i = 0; i < THREADS / 64; ++i) s += ws[i];
        out[0] = s * inv_p;
    }
}

extern "C" void kernel_launch(void* const* d_in, const int* in_sizes, int n_in,
                              void* d_out, int out_size, void* d_ws, size_t ws_size,
                              hipStream_t stream) {
    const float* y = (const float*)d_in[0]; // (B,T,P,3)
    const float* o = (const float*)d_in[1]; // (B,T,P,5)
    int N = in_sizes[1] / 5;                // B*T*P points
    int threads_needed = (N + PTS_PER_THREAD - 1) / PTS_PER_THREAD;
    int blocks = (threads_needed + THREADS - 1) / THREADS;

    float* partial = (float*)d_ws;
    nll_partial_kernel<<<blocks, THREADS, 0, stream>>>(y, o, partial, N);
    // P = 512 (pdf.shape[2] in the reference); 1/512 is exact in fp32.
    nll_final_kernel<<<1, THREADS, 0, stream>>>(partial, blocks, (float*)d_out,
                                                1.0f / 512.0f);
}